// Round 11
// baseline (316.791 us; speedup 1.0000x reference)
//
#include <hip/hip_runtime.h>
#include <hip/hip_fp16.h>

#define NEG_SLOPE 0.2f
#define INVLN2 1.44269504088896f
#define BKT_SHIFT 7
#define BKT_NODES 128
#define BKT_CAP 5120
#define SRC_SHIFT 18
#define SRC_MASK 0x3FFFF
#define CHUNK 4096
#define NBMAX 1024

typedef _Float16 half8 __attribute__((ext_vector_type(8)));
typedef float float4v __attribute__((ext_vector_type(4)));

// ---------------- CSR build, phase A: single-pass register-staged bucket append ----------------
__global__ void k_bucketA(const int* __restrict__ ei, unsigned int* __restrict__ pk,
                          int* __restrict__ bcnt, int E, int NBKT)
{
    __shared__ unsigned int stage[CHUNK];
    __shared__ unsigned short stageB[CHUNK];
    __shared__ int cnt[NBMAX];
    __shared__ int excl[NBMAX];
    __shared__ int curp[NBMAX];
    __shared__ int gbase[NBMAX];

    int t = threadIdx.x;
    int e0 = blockIdx.x * CHUNK;
    bool vec4 = ((E & 3) == 0);

    for (int i = t; i < NBMAX; i += 256) cnt[i] = 0;
    __syncthreads();

    int4 s4[4], d4[4];
    bool val[4];

    if (vec4) {
#pragma unroll
        for (int it = 0; it < 4; it++) {
            int e = e0 + it * 1024 + t * 4;
            val[it] = (e < E);
            if (val[it]) {
                s4[it] = *(const int4*)(ei + e);
                d4[it] = *(const int4*)(ei + (size_t)E + e);
                atomicAdd(&cnt[d4[it].x >> BKT_SHIFT], 1);
                atomicAdd(&cnt[d4[it].y >> BKT_SHIFT], 1);
                atomicAdd(&cnt[d4[it].z >> BKT_SHIFT], 1);
                atomicAdd(&cnt[d4[it].w >> BKT_SHIFT], 1);
            }
        }
    } else {
        for (int i = t; i < CHUNK; i += 256) {
            int e = e0 + i;
            if (e >= E) break;
            atomicAdd(&cnt[ei[E + e] >> BKT_SHIFT], 1);
        }
    }
    __syncthreads();
    for (int i = t; i < NBMAX; i += 256) curp[i] = cnt[i];
    __syncthreads();
    // Hillis-Steele over 1024, 4 elems/thread
    for (int off = 1; off < NBMAX; off <<= 1) {
        int v0 = (t       >= off) ? cnt[t       - off] : 0;
        int v1 = (t + 256 >= off) ? cnt[t + 256 - off] : 0;
        int v2 = (t + 512 >= off) ? cnt[t + 512 - off] : 0;
        int v3 = (t + 768 >= off) ? cnt[t + 768 - off] : 0;
        __syncthreads();
        cnt[t] += v0; cnt[t + 256] += v1; cnt[t + 512] += v2; cnt[t + 768] += v3;
        __syncthreads();
    }
    for (int i = t; i < NBMAX; i += 256) {
        int o = curp[i];
        int ex = cnt[i] - o;
        excl[i] = ex;
        curp[i] = ex;
    }
    __syncthreads();
    for (int b = t; b < NBKT; b += 256) {
        int c = cnt[b] - excl[b];
        gbase[b] = (c > 0) ? atomicAdd(&bcnt[b], c) : 0;
    }
    __syncthreads();
    if (vec4) {
#pragma unroll
        for (int it = 0; it < 4; it++) {
            if (!val[it]) continue;
            int ss[4] = {s4[it].x, s4[it].y, s4[it].z, s4[it].w};
            int dd[4] = {d4[it].x, d4[it].y, d4[it].z, d4[it].w};
#pragma unroll
            for (int k = 0; k < 4; k++) {
                int b = dd[k] >> BKT_SHIFT;
                int p = atomicAdd(&curp[b], 1);
                stage[p] = (unsigned)ss[k] | ((unsigned)(dd[k] & (BKT_NODES - 1)) << SRC_SHIFT);
                stageB[p] = (unsigned short)b;
            }
        }
    } else {
        for (int i = t; i < CHUNK; i += 256) {
            int e = e0 + i;
            if (e >= E) break;
            int s = ei[e], d = ei[E + e];
            int b = d >> BKT_SHIFT;
            int p = atomicAdd(&curp[b], 1);
            stage[p] = (unsigned)s | ((unsigned)(d & (BKT_NODES - 1)) << SRC_SHIFT);
            stageB[p] = (unsigned short)b;
        }
    }
    __syncthreads();
    int total = E - e0; if (total > CHUNK) total = CHUNK;
    for (int i = t; i < total; i += 256) {
        int b = stageB[i];
        int idx = gbase[b] + (i - excl[b]);
        if (idx < BKT_CAP) pk[(size_t)b * BKT_CAP + idx] = stage[i];
    }
}

// ---------------- Fused: CSR build phase B (blocks < NBKT) + node prep layer 1 ----------------
__global__ __launch_bounds__(256) void k_build_node1(
        const unsigned int* __restrict__ pk, const int* __restrict__ bcnt,
        int* __restrict__ rs, int* __restrict__ cur, int* __restrict__ ssrc,
        const float* __restrict__ x, const int* __restrict__ type_ids,
        const float* __restrict__ type_emb, const float* __restrict__ W1,
        const float* __restrict__ a_src1, const float* __restrict__ a_dst1,
        __half2* __restrict__ h1h, float* __restrict__ als1, float* __restrict__ ald1,
        int N, int NBKT)
{
    __shared__ unsigned int vals[BKT_CAP];   // 20 KB
    __shared__ int cnt[BKT_NODES];
    __shared__ int cursor[BKT_NODES];
    __shared__ int orig[BKT_NODES];
    __shared__ int red[256];
    int t = threadIdx.x;

    if (blockIdx.x >= NBKT) {
        // ---- node1 part ----
        int node = (blockIdx.x - NBKT) * 4 + (t >> 6);
        int j = t & 63;
        if (node >= N) return;

        float xin[21];
#pragma unroll
        for (int k = 0; k < 5; k++) xin[k] = x[node * 5 + k];
        int ty = type_ids[node];
#pragma unroll
        for (int k = 0; k < 16; k++) xin[5 + k] = type_emb[ty * 16 + k];

        float h = 0.f;
#pragma unroll
        for (int k = 0; k < 21; k++) h += xin[k] * W1[k * 64 + j];

        float hn = __shfl_xor(h, 1);
        if ((j & 1) == 0)
            h1h[node * 32 + (j >> 1)] = __floats2half2_rn(h, hn);

        int head = j >> 5, lane = j & 31;
        float ps = h * a_src1[head * 32 + lane];
        float pd = h * a_dst1[head * 32 + lane];
#pragma unroll
        for (int m = 16; m >= 1; m >>= 1) { ps += __shfl_xor(ps, m); pd += __shfl_xor(pd, m); }
        if (lane == 0) {
            als1[node * 2 + head] = ps * INVLN2;   // pre-scale for exp2
            ald1[node * 2 + head] = pd * INVLN2;
        }
        return;
    }

    // ---- build part ----
    int b = blockIdx.x;
    int nb = min(bcnt[b], BKT_CAP);

    int part = 0;
    for (int i = t; i < b; i += 256) part += min(bcnt[i], BKT_CAP);
    red[t] = part;
    if (t < BKT_NODES) cnt[t] = 0;
    __syncthreads();
    for (int off = 128; off; off >>= 1) {
        if (t < off) red[t] += red[t + off];
        __syncthreads();
    }
    int bs = red[0];

    const unsigned int* mypk = pk + (size_t)b * BKT_CAP;
    int nb4 = nb & ~3;
    for (int e = t * 4; e < nb4; e += 1024) {
        uint4 v = *(const uint4*)(mypk + e);
        *(uint4*)(vals + e) = v;
        atomicAdd(&cnt[v.x >> SRC_SHIFT], 1);
        atomicAdd(&cnt[v.y >> SRC_SHIFT], 1);
        atomicAdd(&cnt[v.z >> SRC_SHIFT], 1);
        atomicAdd(&cnt[v.w >> SRC_SHIFT], 1);
    }
    for (int e = nb4 + t; e < nb; e += 256) {
        unsigned int v = mypk[e];
        vals[e] = v;
        atomicAdd(&cnt[v >> SRC_SHIFT], 1);
    }
    __syncthreads();
    if (t < BKT_NODES) orig[t] = cnt[t];
    __syncthreads();
    for (int off = 1; off < BKT_NODES; off <<= 1) {
        int v = 0;
        if (t < BKT_NODES && t >= off) v = cnt[t - off];
        __syncthreads();
        if (t < BKT_NODES) cnt[t] += v;
        __syncthreads();
    }
    if (t < BKT_NODES) {
        int c = orig[t];
        int ex = cnt[t] - c;
        cursor[t] = ex;
        int node = (b << BKT_SHIFT) + t;
        if (node < N) { rs[node] = bs + ex; cur[node] = bs + ex + c; }
    }
    __syncthreads();
    for (int e = t; e < nb; e += 256) {
        unsigned int w = vals[e];
        int p = atomicAdd(&cursor[w >> SRC_SHIFT], 1);
        ssrc[bs + p] = (int)(w & SRC_MASK);
    }
}

// ---------------- Gather layer 1 (double-buffered rows, packed-fp16 -> h2 fp16) ----------------
__global__ void k_gather1(const int* __restrict__ rs, const int* __restrict__ cur,
                          const int* __restrict__ ssrc, const float4* __restrict__ h4,
                          const float* __restrict__ als1, const float* __restrict__ ald1,
                          const float* __restrict__ b1, float4* __restrict__ h2h4, int N)
{
    int node = blockIdx.x * 4 + (threadIdx.x >> 6);
    if (node >= N) return;
    int l = threadIdx.x & 63;
    int eg = l >> 3;
    int ch = l & 7;
    int head = ch >> 2;
    float ad = ald1[node * 2 + head];

    int beg = rs[node], end = cur[node];
    int cnt = end - beg;
    __half2 acc2[4];
    acc2[0] = acc2[1] = acc2[2] = acc2[3] = __float2half2_rn(0.f);
    float wsum = 0.f;

    // prologue: stage iteration 0
    int s0c = (eg < cnt) ? ssrc[beg + eg] : node;
    int s1c = (8 + eg < cnt) ? ssrc[beg + 8 + eg] : node;
    float al0c = als1[s0c * 2 + head];
    float al1c = als1[s1c * 2 + head];
    float4 r0c = h4[(size_t)s0c * 8 + ch];
    float4 r1c = h4[(size_t)s1c * 8 + ch];

    for (int base = 0; base < cnt; base += 16) {
        // prefetch next iteration (indices, logits, rows)
        int n0 = base + 16 + eg, n1 = base + 24 + eg;
        int s0n = (n0 < cnt) ? ssrc[beg + n0] : node;
        int s1n = (n1 < cnt) ? ssrc[beg + n1] : node;
        float al0n = als1[s0n * 2 + head];
        float al1n = als1[s1n * 2 + head];
        float4 r0n = h4[(size_t)s0n * 8 + ch];
        float4 r1n = h4[(size_t)s1n * 8 + ch];

        bool v0 = (base + eg) < cnt, v1 = (base + 8 + eg) < cnt;
        float lg0 = al0c + ad; lg0 = (lg0 >= 0.f) ? lg0 : NEG_SLOPE * lg0;
        float lg1 = al1c + ad; lg1 = (lg1 >= 0.f) ? lg1 : NEG_SLOPE * lg1;
        float w0 = v0 ? exp2f(lg0) : 0.f;
        float w1 = v1 ? exp2f(lg1) : 0.f;
        __half2 wh0 = __float2half2_rn(w0);
        __half2 wh1 = __float2half2_rn(w1);
        const __half2* p0 = (const __half2*)&r0c;
        const __half2* p1 = (const __half2*)&r1c;
#pragma unroll
        for (int q = 0; q < 4; q++) {
            acc2[q] = __hfma2(p0[q], wh0, acc2[q]);
            acc2[q] = __hfma2(p1[q], wh1, acc2[q]);
        }
        wsum += w0 + w1;

        s0c = s0n; s1c = s1n; al0c = al0n; al1c = al1n; r0c = r0n; r1c = r1n;
    }
    float acc[8];
#pragma unroll
    for (int q = 0; q < 4; q++) {
        float2 f = __half22float2(acc2[q]);
        acc[2*q] = f.x; acc[2*q+1] = f.y;
    }
#pragma unroll
    for (int m = 8; m <= 32; m <<= 1) {
        wsum += __shfl_xor(wsum, m);
#pragma unroll
        for (int q = 0; q < 8; q++) acc[q] += __shfl_xor(acc[q], m);
    }
    // self loop (fp32)
    {
        float lg = als1[node * 2 + head] + ad;
        lg = (lg >= 0.f) ? lg : NEG_SLOPE * lg;
        float w = exp2f(lg);
        float4 r = h4[(size_t)node * 8 + ch];
        const __half2* p = (const __half2*)&r;
#pragma unroll
        for (int q = 0; q < 4; q++) {
            float2 f = __half22float2(p[q]);
            acc[2*q] += w * f.x; acc[2*q+1] += w * f.y;
        }
        wsum += w;
    }
    float inv = 1.f / (wsum + 1e-16f);
    if (eg == 0) {
        union { float4 f4; __half2 h2[4]; } u;
#pragma unroll
        for (int q = 0; q < 4; q++) {
            float v0 = fmaxf(acc[2*q]   * inv + b1[ch * 8 + 2*q],     0.f);
            float v1 = fmaxf(acc[2*q+1] * inv + b1[ch * 8 + 2*q + 1], 0.f);
            u.h2[q] = __floats2half2_rn(v0, v1);
        }
        h2h4[(size_t)node * 8 + ch] = u.f4;
    }
}

// ---------------- MFMA projection: h3 = h2 @ W2 (fp16 in, fp32 acc) + logits ----------------
__global__ __launch_bounds__(256) void k_node2m(
        const _Float16* __restrict__ h2h, const float* __restrict__ W2,
        const float* __restrict__ a_src2, const float* __restrict__ a_dst2,
        _Float16* __restrict__ h3h, float* __restrict__ als2, float* __restrict__ ald2, int N)
{
    __shared__ _Float16 w2t[64][72];
    __shared__ float h3t[4][16][65];
    int t = threadIdx.x;
    for (int e = t; e < 4096; e += 256) {
        int k = e >> 6, n = e & 63;
        w2t[n][k] = (_Float16)W2[e];
    }
    __syncthreads();

    int w = t >> 6, l = t & 63;
    int l15 = l & 15, quad = l >> 4;
    int nodebase = blockIdx.x * 64 + w * 16;

    int arow = nodebase + l15;
    if (arow >= N) arow = N - 1;
    const half8* ap = (const half8*)(h2h + (size_t)arow * 64 + quad * 8);
    half8 a0 = ap[0];
    half8 a1 = ap[4];
    float4v accs[4];
#pragma unroll
    for (int nt = 0; nt < 4; nt++) {
        half8 b0 = *(const half8*)(&w2t[nt * 16 + l15][quad * 8]);
        half8 b1 = *(const half8*)(&w2t[nt * 16 + l15][32 + quad * 8]);
        float4v c = {0.f, 0.f, 0.f, 0.f};
        c = __builtin_amdgcn_mfma_f32_16x16x32_f16(a0, b0, c, 0, 0, 0);
        c = __builtin_amdgcn_mfma_f32_16x16x32_f16(a1, b1, c, 0, 0, 0);
        accs[nt] = c;
    }
#pragma unroll
    for (int nt = 0; nt < 4; nt++)
#pragma unroll
        for (int r = 0; r < 4; r++)
            h3t[w][quad * 4 + r][nt * 16 + l15] = accs[nt][r];
    __syncthreads();

    int m = l >> 2, part = l & 3;
    int g = blockIdx.x * 64 + w * 16 + m;
    float ps = 0.f, pd = 0.f;
    union { float4 f4[2]; _Float16 h[16]; } u;
#pragma unroll
    for (int c = 0; c < 16; c++) {
        float v = h3t[w][m][part * 16 + c];
        ps += v * a_src2[part * 16 + c];
        pd += v * a_dst2[part * 16 + c];
        u.h[c] = (_Float16)v;
    }
    if (g < N) {
        float4* dst = (float4*)(h3h + (size_t)g * 64) + part * 2;
        dst[0] = u.f4[0];
        dst[1] = u.f4[1];
    }
    ps += __shfl_xor(ps, 1); ps += __shfl_xor(ps, 2);
    pd += __shfl_xor(pd, 1); pd += __shfl_xor(pd, 2);
    if (part == 0 && g < N) { als2[g] = ps * INVLN2; ald2[g] = pd * INVLN2; }
}

// ---------------- Gather layer 2 (double-buffered rows) + LayerNorm ----------------
__global__ void k_gather2(const int* __restrict__ rs, const int* __restrict__ cur,
                          const int* __restrict__ ssrc, const float4* __restrict__ h4,
                          const float* __restrict__ als2, const float* __restrict__ ald2,
                          const float* __restrict__ b2, const float* __restrict__ gamma,
                          const float* __restrict__ beta, float* __restrict__ out, int N)
{
    int node = blockIdx.x * 4 + (threadIdx.x >> 6);
    if (node >= N) return;
    int l = threadIdx.x & 63;
    int eg = l >> 3;
    int ch = l & 7;
    float ad = ald2[node];

    int beg = rs[node], end = cur[node];
    int cnt = end - beg;
    __half2 acc2[4];
    acc2[0] = acc2[1] = acc2[2] = acc2[3] = __float2half2_rn(0.f);
    float wsum = 0.f;

    int s0c = (eg < cnt) ? ssrc[beg + eg] : node;
    int s1c = (8 + eg < cnt) ? ssrc[beg + 8 + eg] : node;
    float al0c = als2[s0c];
    float al1c = als2[s1c];
    float4 r0c = h4[(size_t)s0c * 8 + ch];
    float4 r1c = h4[(size_t)s1c * 8 + ch];

    for (int base = 0; base < cnt; base += 16) {
        int n0 = base + 16 + eg, n1 = base + 24 + eg;
        int s0n = (n0 < cnt) ? ssrc[beg + n0] : node;
        int s1n = (n1 < cnt) ? ssrc[beg + n1] : node;
        float al0n = als2[s0n];
        float al1n = als2[s1n];
        float4 r0n = h4[(size_t)s0n * 8 + ch];
        float4 r1n = h4[(size_t)s1n * 8 + ch];

        bool v0 = (base + eg) < cnt, v1 = (base + 8 + eg) < cnt;
        float lg0 = al0c + ad; lg0 = (lg0 >= 0.f) ? lg0 : NEG_SLOPE * lg0;
        float lg1 = al1c + ad; lg1 = (lg1 >= 0.f) ? lg1 : NEG_SLOPE * lg1;
        float w0 = v0 ? exp2f(lg0) : 0.f;
        float w1 = v1 ? exp2f(lg1) : 0.f;
        __half2 wh0 = __float2half2_rn(w0);
        __half2 wh1 = __float2half2_rn(w1);
        const __half2* p0 = (const __half2*)&r0c;
        const __half2* p1 = (const __half2*)&r1c;
#pragma unroll
        for (int q = 0; q < 4; q++) {
            acc2[q] = __hfma2(p0[q], wh0, acc2[q]);
            acc2[q] = __hfma2(p1[q], wh1, acc2[q]);
        }
        wsum += w0 + w1;

        s0c = s0n; s1c = s1n; al0c = al0n; al1c = al1n; r0c = r0n; r1c = r1n;
    }
    float acc[8];
#pragma unroll
    for (int q = 0; q < 4; q++) {
        float2 f = __half22float2(acc2[q]);
        acc[2*q] = f.x; acc[2*q+1] = f.y;
    }
#pragma unroll
    for (int m = 8; m <= 32; m <<= 1) {
        wsum += __shfl_xor(wsum, m);
#pragma unroll
        for (int q = 0; q < 8; q++) acc[q] += __shfl_xor(acc[q], m);
    }
    // self loop (fp32)
    {
        float lg = als2[node] + ad;
        lg = (lg >= 0.f) ? lg : NEG_SLOPE * lg;
        float w = exp2f(lg);
        float4 r = h4[(size_t)node * 8 + ch];
        const __half2* p = (const __half2*)&r;
#pragma unroll
        for (int q = 0; q < 4; q++) {
            float2 f = __half22float2(p[q]);
            acc[2*q] += w * f.x; acc[2*q+1] += w * f.y;
        }
        wsum += w;
    }
    float inv = 1.f / (wsum + 1e-16f);
    float o[8];
    float s = 0.f;
#pragma unroll
    for (int q = 0; q < 8; q++) { o[q] = acc[q] * inv + b2[ch * 8 + q]; s += o[q]; }
#pragma unroll
    for (int m = 1; m <= 4; m <<= 1) s += __shfl_xor(s, m);
    float mu = s * (1.f / 64.f);
    float v = 0.f;
#pragma unroll
    for (int q = 0; q < 8; q++) { float d = o[q] - mu; v += d * d; }
#pragma unroll
    for (int m = 1; m <= 4; m <<= 1) v += __shfl_xor(v, m);
    v *= (1.f / 64.f);
    float r = rsqrtf(v + 1e-5f);
    if (eg == 0) {
        float res[8];
#pragma unroll
        for (int q = 0; q < 8; q++)
            res[q] = (o[q] - mu) * r * gamma[ch * 8 + q] + beta[ch * 8 + q];
        float4* op = (float4*)(out + (size_t)node * 64 + ch * 8);
        op[0] = make_float4(res[0], res[1], res[2], res[3]);
        op[1] = make_float4(res[4], res[5], res[6], res[7]);
    }
}

extern "C" void kernel_launch(void* const* d_in, const int* in_sizes, int n_in,
                              void* d_out, int out_size, void* d_ws, size_t ws_size,
                              hipStream_t stream) {
    const float* x        = (const float*)d_in[0];
    const int*   ei       = (const int*)  d_in[1];
    const int*   type_ids = (const int*)  d_in[2];
    const float* type_emb = (const float*)d_in[3];
    const float* W1       = (const float*)d_in[4];
    const float* a_src1   = (const float*)d_in[5];
    const float* a_dst1   = (const float*)d_in[6];
    const float* b1       = (const float*)d_in[7];
    const float* W2       = (const float*)d_in[8];
    const float* a_src2   = (const float*)d_in[9];
    const float* a_dst2   = (const float*)d_in[10];
    const float* b2       = (const float*)d_in[11];
    const float* gamma    = (const float*)d_in[12];
    const float* beta     = (const float*)d_in[13];

    int N = in_sizes[0] / 5;
    int E = in_sizes[1] / 2;
    int NBKT = (N + BKT_NODES - 1) >> BKT_SHIFT;

    // Workspace: pk (16 MB, dead after build) overlaid on h2h/h3h (25.6 MB).
    char* base = (char*)d_ws;
    size_t off = 0;
    auto carve = [&](size_t bytes) { void* p = base + off; off += (bytes + 255) & ~(size_t)255; return p; };
    __half2* h1h = (__half2*)carve((size_t)N * 64 * sizeof(__half));
    size_t pk_bytes = (size_t)NBKT * BKT_CAP * sizeof(unsigned int);
    size_t h23_bytes = 2 * (size_t)N * 64 * sizeof(__half);
    char* uni = (char*)carve(pk_bytes > h23_bytes ? pk_bytes : h23_bytes);
    _Float16* h2h = (_Float16*)uni;
    _Float16* h3h = (_Float16*)(uni + (size_t)N * 64 * sizeof(__half));
    unsigned int* pk = (unsigned int*)uni;
    float* als1  = (float*)carve((size_t)N * 2 * sizeof(float));
    float* ald1  = (float*)carve((size_t)N * 2 * sizeof(float));
    float* als2  = (float*)carve((size_t)N * sizeof(float));
    float* ald2  = (float*)carve((size_t)N * sizeof(float));
    int*   rs    = (int*)carve((size_t)N * sizeof(int));
    int*   cur   = (int*)carve((size_t)N * sizeof(int));
    int*   bcnt  = (int*)carve(1024 * sizeof(int));
    int*   ssrc  = (int*)carve((size_t)E * sizeof(int));

    dim3 tb(256);
    dim3 nb((N + 3) / 4);
    int nodeBlocks = (N + 3) / 4;

    hipMemsetAsync(bcnt, 0, NBKT * sizeof(int), stream);
    k_bucketA<<<dim3((E + CHUNK - 1) / CHUNK), tb, 0, stream>>>(ei, pk, bcnt, E, NBKT);

    // fused: CSR phase B (first NBKT blocks) + node1 features/logits (rest)
    k_build_node1<<<dim3(NBKT + nodeBlocks), tb, 0, stream>>>(
        pk, bcnt, rs, cur, ssrc,
        x, type_ids, type_emb, W1, a_src1, a_dst1, h1h, als1, ald1,
        N, NBKT);

    k_gather1<<<nb, tb, 0, stream>>>(rs, cur, ssrc, (const float4*)h1h, als1, ald1, b1,
                                     (float4*)h2h, N);
    k_node2m<<<dim3((N + 63) / 64), tb, 0, stream>>>(h2h, W2, a_src2, a_dst2,
                                                     h3h, als2, ald2, N);
    k_gather2<<<nb, tb, 0, stream>>>(rs, cur, ssrc, (const float4*)h3h, als2, ald2, b2,
                                     gamma, beta, (float*)d_out, N);
}